// Round 3
// baseline (277.678 us; speedup 1.0000x reference)
//
#include <hip/hip_runtime.h>

#define BATCH 50
#define MAX_ATOMS 21000
#define DIM 128
#define ROW4 (DIM / 4)                      // 32 float4 per feature row
#define TOTAL4 (BATCH * MAX_ATOMS * ROW4)   // 33,600,000 float4 outputs
#define SAMPLES 2048
#define F4_PER_THREAD 8
#define BLOCK 256
#define F4_PER_BLOCK (BLOCK * F4_PER_THREAD)  // 2048

typedef float f4 __attribute__((ext_vector_type(4)));

// Kernel 1: starts[b] = lower_bound(idx, b) for b in [0, BATCH].
// Hierarchical: detect int32-vs-int64 storage, sample 2048 points into LDS
// (one parallel round trip), then 51 threads binary-search a ~489-wide
// bracket (~9 serial, mostly L2-resident, iterations).
__global__ __launch_bounds__(1024) void compute_starts_kernel(
        const int* __restrict__ idx32, int N, int* __restrict__ starts) {
    __shared__ int s_flag;
    __shared__ int samp[SAMPLES];

    // int64 detection: sorted int64 little-endian viewed as int32 gives
    // [v,0,v,0,...] -> a descending adjacent pair near the middle.
    if (threadIdx.x < 64) {
        int base = N / 2;
        int a = idx32[base + threadIdx.x];
        int c = idx32[base + threadIdx.x + 1];
        unsigned long long m = __ballot(a > c);
        if (threadIdx.x == 0) s_flag = (m != 0ull) ? 1 : 0;
    }
    __syncthreads();
    const int stride = s_flag ? 2 : 1;   // word stride to the value word
    const int step = (N + SAMPLES - 1) / SAMPLES;

    // coarse sampling: 1024 threads x 2 samples
    for (int t = threadIdx.x; t < SAMPLES; t += 1024) {
        int i = t * step; if (i > N - 1) i = N - 1;
        samp[t] = idx32[(long)i * stride];
    }
    __syncthreads();

    int b = threadIdx.x;
    if (b <= BATCH) {
        // coarse: first sample index u with samp[u] >= b (u in [0, SAMPLES])
        int ulo = 0, uhi = SAMPLES;
        while (ulo < uhi) {
            int m = (ulo + uhi) >> 1;
            if (samp[m] < b) ulo = m + 1; else uhi = m;
        }
        int lo, hi;
        if (ulo == 0) { lo = 0; hi = 1; }
        else {
            int j = (ulo - 1) * step; if (j > N - 1) j = N - 1;
            lo = j + 1;
            if (ulo == SAMPLES) hi = N;
            else { int k = ulo * step; if (k > N - 1) k = N - 1; hi = k + 1; }
        }
        // fine: lower_bound within [lo, hi)
        while (lo < hi) {
            int m = (lo + hi) >> 1;
            if (idx32[(long)m * stride] < b) lo = m + 1; else hi = m;
        }
        starts[b] = lo;
    }
}

// Kernel 2: gather-style padded write, 8 float4 per thread, NT streams.
// out[b][p][q] = (p < count[b]) ? feat[(starts[b]+p)*ROW4 + q] : 0
__global__ __launch_bounds__(BLOCK) void gather_pad_kernel(
        const f4* __restrict__ feat,
        const int* __restrict__ starts,
        f4* __restrict__ out) {
    __shared__ int s_starts[BATCH + 1];
    if (threadIdx.x <= BATCH) s_starts[threadIdx.x] = starts[threadIdx.x];
    __syncthreads();

    unsigned int base = blockIdx.x * (unsigned)F4_PER_BLOCK + threadIdx.x;

    f4 v[F4_PER_THREAD];
    bool ok[F4_PER_THREAD];
#pragma unroll
    for (int k = 0; k < F4_PER_THREAD; ++k) {
        unsigned int gid = base + (unsigned)k * BLOCK;
        ok[k] = gid < (unsigned)TOTAL4;
        v[k] = (f4)(0.0f);
        if (ok[k]) {
            unsigned int q   = gid & (ROW4 - 1);
            unsigned int row = gid >> 5;              // b * MAX_ATOMS + p
            unsigned int b   = row / MAX_ATOMS;       // magic-mul
            unsigned int p   = row - b * MAX_ATOMS;
            int s = s_starts[b];
            int e = s_starts[b + 1];
            if ((int)p < e - s)
                v[k] = __builtin_nontemporal_load(feat + (long)(s + (int)p) * ROW4 + q);
        }
    }
#pragma unroll
    for (int k = 0; k < F4_PER_THREAD; ++k) {
        unsigned int gid = base + (unsigned)k * BLOCK;
        if (ok[k]) __builtin_nontemporal_store(v[k], out + gid);
    }
}

extern "C" void kernel_launch(void* const* d_in, const int* in_sizes, int n_in,
                              void* d_out, int out_size, void* d_ws, size_t ws_size,
                              hipStream_t stream) {
    const float* feat = (const float*)d_in[0];
    const int*   idx  = (const int*)d_in[1];
    int N = in_sizes[1];                    // 1,000,000 atoms

    int* starts = (int*)d_ws;               // BATCH+1 ints of scratch

    compute_starts_kernel<<<1, 1024, 0, stream>>>(idx, N, starts);

    const int grid = (TOTAL4 + F4_PER_BLOCK - 1) / F4_PER_BLOCK;
    gather_pad_kernel<<<grid, BLOCK, 0, stream>>>(
        (const f4*)feat, starts, (f4*)d_out);
}

// Round 4
// 182.372 us; speedup vs baseline: 1.5226x; 1.5226x over previous
//
#include <hip/hip_runtime.h>
#include <limits.h>

#define BATCH 50
#define MAX_ATOMS 21000
#define DIM 128
#define ROW4 (DIM / 4)                      // 32 float4 per feature row
#define TOTAL4 (BATCH * MAX_ATOMS * ROW4)   // 33,600,000 float4 outputs
#define BLOCK 256
#define F4_PER_THREAD 4
#define F4_PER_BLOCK (BLOCK * F4_PER_THREAD)  // 1024

typedef float f4 __attribute__((ext_vector_type(4)));

// Kernel 1: starts[b] = lower_bound(idx, b), one wave per b, 64-ary search.
// Each probe round narrows the bracket by 64x -> 4 dependent HBM round trips
// (1M -> 15625 -> 245 -> 4 -> done) instead of ~9 serial binary-search loads.
// Handles int32 or int64 index storage (int64 little-endian small values
// viewed as int32 -> descending adjacent pair near the middle).
__global__ __launch_bounds__(1024) void compute_starts_kernel(
        const int* __restrict__ idx32, int N, int* __restrict__ starts) {
    const int lane = threadIdx.x & 63;
    const int b = (int)(blockIdx.x * 16u + (threadIdx.x >> 6));  // wave id
    if (b > BATCH) return;

    // int64 storage detection (uniform result per wave via ballot)
    int base = N / 2;
    int a0 = idx32[base + lane];
    int a1 = idx32[base + lane + 1];
    const int stride = (__ballot(a0 > a1) != 0ull) ? 2 : 1;

    long L = 0, H = N;   // lower_bound(idx, b) is in [L, H]
    while (H - L > 64) {
        long len = H - L;
        long step = (len + 63) >> 6;          // ceil(len/64)
        long p = L + (long)lane * step;
        int v = (p < H) ? idx32[p * stride] : INT_MAX;
        int c = __popcll(__ballot(v < b));
        long oldL = L;
        if (c == 0) { H = L; break; }         // answer == L
        L = oldL + (long)(c - 1) * step + 1;
        long nh = oldL + (long)c * step;
        if (nh < H) H = nh;
    }
    // final round: bracket width <= 64
    long p = L + lane;
    int v = (p < H) ? idx32[p * stride] : INT_MAX;
    int c = __popcll(__ballot(v < b));
    if (lane == 0) starts[b] = (int)(L + c);
}

// Kernel 2: gather-style padded write, 4 float4 per thread, NT streams,
// load+store paired per iteration (proven fastest shape, R2).
// out[b][p][q] = (p < count[b]) ? feat[(starts[b]+p)*ROW4 + q] : 0
__global__ __launch_bounds__(BLOCK) void gather_pad_kernel(
        const f4* __restrict__ feat,
        const int* __restrict__ starts,
        f4* __restrict__ out) {
    __shared__ int s_starts[BATCH + 1];
    if (threadIdx.x <= BATCH) s_starts[threadIdx.x] = starts[threadIdx.x];
    __syncthreads();

    unsigned int base = blockIdx.x * (unsigned)F4_PER_BLOCK + threadIdx.x;
#pragma unroll
    for (int k = 0; k < F4_PER_THREAD; ++k) {
        unsigned int gid = base + (unsigned)k * BLOCK;
        if (gid < (unsigned)TOTAL4) {
            unsigned int q   = gid & (ROW4 - 1);
            unsigned int row = gid >> 5;              // b * MAX_ATOMS + p
            unsigned int b   = row / MAX_ATOMS;       // magic-mul
            unsigned int p   = row - b * MAX_ATOMS;
            int s = s_starts[b];
            int e = s_starts[b + 1];
            f4 v = (f4)(0.0f);
            if ((int)p < e - s)
                v = __builtin_nontemporal_load(feat + (long)(s + (int)p) * ROW4 + q);
            __builtin_nontemporal_store(v, out + gid);
        }
    }
}

extern "C" void kernel_launch(void* const* d_in, const int* in_sizes, int n_in,
                              void* d_out, int out_size, void* d_ws, size_t ws_size,
                              hipStream_t stream) {
    const float* feat = (const float*)d_in[0];
    const int*   idx  = (const int*)d_in[1];
    int N = in_sizes[1];                    // 1,000,000 atoms

    int* starts = (int*)d_ws;               // BATCH+1 ints of scratch

    // 4 blocks x 16 waves = 64 waves >= 51 searches
    compute_starts_kernel<<<4, 1024, 0, stream>>>(idx, N, starts);

    const int grid = (TOTAL4 + F4_PER_BLOCK - 1) / F4_PER_BLOCK;
    gather_pad_kernel<<<grid, BLOCK, 0, stream>>>(
        (const f4*)feat, starts, (f4*)d_out);
}